// Round 4
// baseline (1497.943 us; speedup 1.0000x reference)
//
#include <hip/hip_runtime.h>

#define NC 512   // N_CLUSTERS

// ---------------------------------------------------------------------------
// Stage 1: discretize — argmin over 512 centroids (verified R1).
// ---------------------------------------------------------------------------
__global__ __launch_bounds__(256) void k_discretize(
    const float* __restrict__ x, const float* __restrict__ cent, int* __restrict__ out)
{
    __shared__ float c[NC];
    int tid = threadIdx.x;
    for (int i = tid; i < NC; i += 256) c[i] = cent[i];
    __syncthreads();
    int id = blockIdx.x * 256 + tid;   // 131072 exact
    float px = x[id];
    float best = fabsf(px - c[0]);
    int bi = 0;
    for (int k = 1; k < NC; ++k) {
        float d = fabsf(px - c[k]);
        if (d < best) { best = d; bi = k; }
    }
    out[id] = bi;
}

// ---------------------------------------------------------------------------
// Nibble-bin pop-min scanner. 512 bins packed 8-per-u32 (64 words/lane, padded
// region stride supplied by caller). Window = 4 VGPRs (ds_read_b128) = 32 bins
// + 32-bit nonzero mask; pops/peeks are pure VALU. Build and out-of-window
// inserts use fire-and-forget ds_add (atomicAdd, result unused) => no RMW
// latency chain. DS pipe is in-order per lane, so later window loads see them.
// ---------------------------------------------------------------------------
struct ScanN {
    uint32_t* base;    // lane's 64-word nibble-bin region
    uint32_t w[4];
    uint32_t mask;     // bit k <=> bin (chunk*32+k) nonzero
    int chunk;

    static __device__ inline uint32_t nz4b(uint32_t x) {   // byte-nonzero -> 4 bits
        uint32_t y = (x & 0x7F7F7F7Fu) + 0x7F7F7F7Fu;
        y = (y | x) & 0x80808080u;
        return (y * 0x00204081u) >> 28;
    }
    static __device__ inline uint32_t spread4(uint32_t v) { // 4 bits -> even positions
        v = (v | (v << 2)) & 0x33u;
        v = (v | (v << 1)) & 0x55u;
        return v;
    }
    static __device__ inline uint32_t nzn(uint32_t x) {    // per-nibble nonzero -> 8 bits
        uint32_t lo = x & 0x0F0F0F0Fu;
        uint32_t hi = (x >> 4) & 0x0F0F0F0Fu;
        return spread4(nz4b(lo)) | (spread4(nz4b(hi)) << 1);
    }
    __device__ inline void init(uint32_t* b) { base = b; mask = 0; chunk = -1; }
    __device__ inline void load() {
        uint4 a = *(const uint4*)(base + chunk * 4);
        w[0] = a.x; w[1] = a.y; w[2] = a.z; w[3] = a.w;
        mask = nzn(w[0]) | (nzn(w[1]) << 8) | (nzn(w[2]) << 16) | (nzn(w[3]) << 24);
    }
    __device__ inline void ensure() { while (mask == 0) { ++chunk; load(); } }
    __device__ inline int  peek()   { ensure(); return chunk * 32 + (int)__builtin_ctz(mask); }
    __device__ inline void consume_min() {          // precondition: mask != 0
        int k = (int)__builtin_ctz(mask);
        int dw = k >> 3, sh = (k & 7) << 2;
        uint32_t cnt = 0;
#pragma unroll
        for (int i = 0; i < 4; ++i) if (i == dw) { cnt = (w[i] >> sh) & 0xFu; w[i] -= (1u << sh); }
        if (cnt == 1) mask &= ~(1u << k);
    }
    __device__ inline int pop() { int v = peek(); consume_min(); return v; }
    __device__ inline void insert(int v) {          // precondition: v > current min
        int rel = v - chunk * 32;
        if (rel < 32) {
            int dw = rel >> 3, sh = (rel & 7) << 2;
#pragma unroll
            for (int i = 0; i < 4; ++i) if (i == dw) w[i] += (1u << sh);
            mask |= (1u << rel);
        } else {
            atomicAdd(&base[v >> 3], 1u << ((v & 7) << 2));   // future window
        }
    }
};

// ---------------------------------------------------------------------------
// Symbolic conv (k=5, s=2), _conv_reduce semantics (verified R1/R2).
// TWO instances per lane: two independent fold chains double MLP at the same
// 32 KB LDS / occupancy. Lane region stride 132 words (528 B, 16B-aligned,
// bank offset tid*4 -> 8-way window-load conflicts instead of 32-way).
// ---------------------------------------------------------------------------
template<int K, int CIN, int CO, int IH, int IW, int OH, int OW>
__global__ __launch_bounds__(64) void k_conv(
    const int* __restrict__ in_sym,    // (B, IH, IW, CIN)
    const int* __restrict__ wsym,      // (N, CO)
    const int* __restrict__ conv_lut,  // (NC, NC)
    const int* __restrict__ add_lut,   // (NC, NC)
    const int* __restrict__ bias_lut,  // (NC, CO)
    const int* __restrict__ relu_lut,  // (NC,)
    int* __restrict__ out)             // (B, OH, OW, CO)
{
    constexpr int N = K * K * CIN;
    constexpr int STRIDE = 132;                       // words per lane region pair
    __shared__ __align__(16) uint32_t bins[64 * STRIDE];   // 33 KB
    int tid = threadIdx.x;

    uint4* bz = (uint4*)bins;
    for (int i = tid; i < 64 * STRIDE / 4; i += 64) bz[i] = uint4{0, 0, 0, 0};
    __syncthreads();

    uint32_t* reg0 = bins + tid * STRIDE;        // inst 0: words [0,64)
    uint32_t* reg1 = reg0 + 64;                  // inst 1: words [64,128)

    int id0 = blockIdx.x * 128 + tid;            // instance ids: id0, id0+64
#pragma unroll
    for (int u = 0; u < 2; ++u) {
        int id = id0 + u * 64;
        int co = id % CO;
        int r  = id / CO;
        int ox = r % OW; r /= OW;
        int oy = r % OH;
        int b  = r / OH;
        uint32_t* mybins = u ? reg1 : reg0;
        for (int n = 0; n < N; ++n) {
            int i   = n / (K * CIN);
            int rem = n % (K * CIN);
            int j   = rem / CIN;
            int c   = rem % CIN;
            int s = in_sym[((b * IH + (oy * 2 + i)) * IW + (ox * 2 + j)) * CIN + c];
            int w = wsym[n * CO + co];
            int g = conv_lut[s * NC + w];
            atomicAdd(&mybins[g >> 3], 1u << ((g & 7) << 2));   // fire-and-forget
        }
    }

    ScanN sc[2];
    sc[0].init(reg0); sc[1].init(reg1);
    int t[2], x[2], t2[2];
#pragma unroll
    for (int u = 0; u < 2; ++u) t[u] = sc[u].pop();
    for (int j = 1; j < N; ++j) {
#pragma unroll
        for (int u = 0; u < 2; ++u) x[u] = sc[u].pop();
#pragma unroll
        for (int u = 0; u < 2; ++u) t2[u] = add_lut[x[u] * NC + t[u]];  // 2 loads in flight
        if (j < N - 2) {
#pragma unroll
            for (int u = 0; u < 2; ++u) {
                int y = sc[u].peek();
                if (t2[u] > y) { sc[u].consume_min(); sc[u].insert(t2[u]); t[u] = y; }
                else t[u] = t2[u];
            }
        } else {
            t[0] = t2[0]; t[1] = t2[1];
        }
    }
#pragma unroll
    for (int u = 0; u < 2; ++u) {
        int id = id0 + u * 64;
        int co = id % CO;
        out[id] = relu_lut[bias_lut[t[u] * CO + co]];
    }
}

// ---------------------------------------------------------------------------
// Symbolic FC, _fc_reduce = ascending pops (verified R1/R2). One instance per
// lane (grids are small); nibble bins, stride 68 words (272 B, 16B-aligned).
// ---------------------------------------------------------------------------
template<int M, int K, bool PERM>
__global__ __launch_bounds__(64) void k_fc(
    const int* __restrict__ in_sym,
    const int* __restrict__ wsym,      // (M, K)
    const int* __restrict__ fc_lut,    // (NC, NC)
    const int* __restrict__ add_lut,   // (NC, NC)
    const int* __restrict__ bias_lut,  // (NC, M)
    const int* __restrict__ relu_lut,  // (NC,)
    int* __restrict__ out)             // (B, M)
{
    constexpr int STRIDE = 68;
    __shared__ __align__(16) uint32_t bins[64 * STRIDE];   // 17 KB
    int tid = threadIdx.x;
    uint4* bz = (uint4*)bins;
    for (int i = tid; i < 64 * STRIDE / 4; i += 64) bz[i] = uint4{0, 0, 0, 0};
    __syncthreads();

    int id = blockIdx.x * 64 + tid;
    int m = id % M;
    int b = id / M;

    uint32_t* mybins = bins + tid * STRIDE;
    for (int k = 0; k < K; ++k) {
        int xaddr;
        if (PERM) { int c = k / 25, yx = k % 25; xaddr = b * 400 + yx * 16 + c; }
        else      { xaddr = b * K + k; }
        int v = fc_lut[in_sym[xaddr] * NC + wsym[m * K + k]];
        atomicAdd(&mybins[v >> 3], 1u << ((v & 7) << 2));
    }

    ScanN sc; sc.init(mybins);
    int t = sc.pop();
    for (int s = 1; s < K; ++s) t = add_lut[sc.pop() * NC + t];
    out[id] = relu_lut[bias_lut[t * M + m]];
}

// ---------------------------------------------------------------------------
// Head: feats = centroid[sym], logits = feats @ W^T + b, softmax (verified R1).
// ---------------------------------------------------------------------------
__global__ __launch_bounds__(64) void k_head(
    const int* __restrict__ f2_syms,   // (128, 84)
    const float* __restrict__ cent,    // (NC,)
    const float* __restrict__ w,       // (10, 84)
    const float* __restrict__ bias,    // (10,)
    float* __restrict__ out)           // (128, 10)
{
    int b = blockIdx.x * 64 + threadIdx.x;
    float acc[10];
#pragma unroll
    for (int o = 0; o < 10; ++o) acc[o] = bias[o];
    for (int k = 0; k < 84; ++k) {
        float f = cent[f2_syms[b * 84 + k]];
#pragma unroll
        for (int o = 0; o < 10; ++o) acc[o] += f * w[o * 84 + k];
    }
    float mx = acc[0];
#pragma unroll
    for (int o = 1; o < 10; ++o) mx = fmaxf(mx, acc[o]);
    float s = 0.f;
#pragma unroll
    for (int o = 0; o < 10; ++o) { acc[o] = expf(acc[o] - mx); s += acc[o]; }
    float inv = 1.f / s;
#pragma unroll
    for (int o = 0; o < 10; ++o) out[b * 10 + o] = acc[o] * inv;
}

// ---------------------------------------------------------------------------
extern "C" void kernel_launch(void* const* d_in, const int* in_sizes, int n_in,
                              void* d_out, int out_size, void* d_ws, size_t ws_size,
                              hipStream_t stream)
{
    const float* x_bat  = (const float*)d_in[0];
    const float* cent   = (const float*)d_in[1];
    const int* conv_lut = (const int*)d_in[2];
    const int* fc_lut   = (const int*)d_in[3];
    const int* add_lut  = (const int*)d_in[4];
    const int* relu_lut = (const int*)d_in[5];
    const int* c1_bias  = (const int*)d_in[6];
    const int* c2_bias  = (const int*)d_in[7];
    const int* f1_bias  = (const int*)d_in[8];
    const int* f2_bias  = (const int*)d_in[9];
    const int* c1f      = (const int*)d_in[10];
    const int* c2f      = (const int*)d_in[11];
    const int* f1f      = (const int*)d_in[12];
    const int* f2f      = (const int*)d_in[13];
    const float* fc3_w  = (const float*)d_in[14];
    const float* fc3_b  = (const float*)d_in[15];
    float* out = (float*)d_out;

    char* ws = (char*)d_ws;
    int* sym0 = (int*)(ws);                                   // 128*32*32
    int* c1o  = (int*)(ws + 524288);                          // 128*14*14*6
    int* c2o  = (int*)(ws + 524288 + 602112);                 // 128*5*5*16
    int* f1o  = (int*)(ws + 524288 + 602112 + 204800);        // 128*120
    int* f2o  = (int*)(ws + 524288 + 602112 + 204800 + 61440);// 128*84

    k_discretize<<<512, 256, 0, stream>>>(x_bat, cent, sym0);
    k_conv<5, 1, 6, 32, 32, 14, 14><<<150528 / 128, 64, 0, stream>>>(
        sym0, c1f, conv_lut, add_lut, c1_bias, relu_lut, c1o);
    k_conv<5, 6, 16, 14, 14, 5, 5><<<51200 / 128, 64, 0, stream>>>(
        c1o, c2f, conv_lut, add_lut, c2_bias, relu_lut, c2o);
    k_fc<120, 400, true><<<15360 / 64, 64, 0, stream>>>(
        c2o, f1f, fc_lut, add_lut, f1_bias, relu_lut, f1o);
    k_fc<84, 120, false><<<10752 / 64, 64, 0, stream>>>(
        f1o, f2f, fc_lut, add_lut, f2_bias, relu_lut, f2o);
    k_head<<<2, 64, 0, stream>>>(f2o, cent, fc3_w, fc3_b, out);
}

// Round 5
// 999.188 us; speedup vs baseline: 1.4992x; 1.4992x over previous
//
#include <hip/hip_runtime.h>

#define NC 512   // N_CLUSTERS

// ===========================================================================
// Pre-pass: convT[w][s] = (u16)conv_lut[s][w]  (verified correct in R3 run).
// ===========================================================================
__global__ __launch_bounds__(256) void k_transpose_pack(
    const int* __restrict__ src, unsigned short* __restrict__ dst)
{
    __shared__ unsigned short tile[64][65];
    int tx = blockIdx.x % 8, ty = blockIdx.x / 8;
    int lane = threadIdx.x & 63, grp = threadIdx.x >> 6;
    for (int r = grp * 16; r < grp * 16 + 16; ++r)
        tile[r][lane] = (unsigned short)src[(ty * 64 + r) * NC + tx * 64 + lane];
    __syncthreads();
    for (int r = grp * 16; r < grp * 16 + 16; ++r)
        dst[(tx * 64 + r) * NC + ty * 64 + lane] = tile[lane][r];
}

// ===========================================================================
// Stage 1: discretize -> u16 symbols (R1-verified logic).
// ===========================================================================
__global__ __launch_bounds__(256) void k_discretize(
    const float* __restrict__ x, const float* __restrict__ cent,
    unsigned short* __restrict__ out)
{
    __shared__ float c[NC];
    int tid = threadIdx.x;
    for (int i = tid; i < NC; i += 256) c[i] = cent[i];
    __syncthreads();
    int id = blockIdx.x * 256 + tid;   // 131072 exact
    float px = x[id];
    float best = fabsf(px - c[0]);
    int bi = 0;
    for (int k = 1; k < NC; ++k) {
        float d = fabsf(px - c[k]);
        if (d < best) { best = d; bi = k; }
    }
    out[id] = (unsigned short)bi;
}

// ===========================================================================
// Register-window pop-min scanner — R2 verbatim (verified).
// ===========================================================================
struct ScanU8 {
    unsigned char* base;
    uint32_t w[8];
    uint32_t mask;
    int chunk;

    static __device__ inline uint32_t nz4(uint32_t x) {
        uint32_t y = (x & 0x7F7F7F7Fu) + 0x7F7F7F7Fu;
        y = (y | x) & 0x80808080u;
        return (y * 0x00204081u) >> 28;
    }
    __device__ inline void init(unsigned char* b) { base = b; mask = 0; chunk = -1; }
    __device__ inline void load() {
        const uint4* p = (const uint4*)(base + chunk * 32);
        uint4 a = p[0], b2 = p[1];
        w[0]=a.x; w[1]=a.y; w[2]=a.z; w[3]=a.w;
        w[4]=b2.x; w[5]=b2.y; w[6]=b2.z; w[7]=b2.w;
        mask =  nz4(w[0])        | (nz4(w[1]) << 4)  | (nz4(w[2]) << 8)  | (nz4(w[3]) << 12)
             | (nz4(w[4]) << 16) | (nz4(w[5]) << 20) | (nz4(w[6]) << 24) | (nz4(w[7]) << 28);
    }
    __device__ inline void ensure() { while (mask == 0) { ++chunk; load(); } }
    __device__ inline int  peek()   { ensure(); return chunk * 32 + (int)__builtin_ctz(mask); }
    __device__ inline void consume_min() {
        int k = (int)__builtin_ctz(mask);
        int dw = k >> 2, sh = (k & 3) << 3;
        uint32_t cnt = 0;
#pragma unroll
        for (int i = 0; i < 8; ++i) if (i == dw) { cnt = (w[i] >> sh) & 0xFFu; w[i] -= (1u << sh); }
        if (cnt == 1) mask &= ~(1u << k);
    }
    __device__ inline int pop() { int v = peek(); consume_min(); return v; }
    __device__ inline void insert(int v) {
        int rel = v - chunk * 32;
        if (rel < 32) {
            int dw = rel >> 2, sh = (rel & 3) << 3;
#pragma unroll
            for (int i = 0; i < 8; ++i) if (i == dw) w[i] += (1u << sh);
            mask |= (1u << rel);
        } else {
            base[v] = (unsigned char)(base[v] + 1);
        }
    }
};

// ===========================================================================
// Symbolic conv, _conv_reduce semantics (R1/R2-verified fold). CHANGE vs R2:
// block = (one co) x (64 positions) => build row convT[w][*] is wave-uniform
// (<=16 lines/gather vs 64), rows L1-reuse across same-co blocks.
// ===========================================================================
template<typename IT, typename OT, int CIN, int CO, int IH, int IW, int OH, int OW>
__device__ __forceinline__ void conv_body(
    const IT* __restrict__ in_sym,              // (B, IH, IW, CIN)
    const int* __restrict__ wsym,               // (25*CIN, CO)
    const unsigned short* __restrict__ convT,   // (NC, NC) [w][s]
    const int* __restrict__ add_lut,            // (NC, NC)
    const int* __restrict__ bias_lut,           // (NC, CO)
    const int* __restrict__ relu_lut,           // (NC,)
    OT* __restrict__ out)                       // (B, OH, OW, CO)
{
    constexpr int N   = 25 * CIN;
    constexpr int PPI = OH * OW;
    constexpr int BPC = (128 * PPI) / 64;       // blocks per co (exact)
    __shared__ __align__(16) unsigned char bins[64 * NC];   // 32 KB
    int tid = threadIdx.x;

    uint32_t* bz = (uint32_t*)bins;
    for (int i = 0; i < 128; ++i) bz[i * 64 + tid] = 0u;    // lane-private, 1 wave

    int posg = blockIdx.x % BPC;
    int co   = blockIdx.x / BPC;                // wave-uniform
    int pos  = posg * 64 + tid;
    int b  = pos / PPI;
    int yx = pos % PPI;
    int oy = yx / OW, ox = yx % OW;

    unsigned char* mybins = bins + tid * NC;
    for (int n = 0; n < N; ++n) {
        int i   = n / (5 * CIN);
        int rem = n % (5 * CIN);
        int j   = rem / CIN;
        int c   = rem % CIN;
        int s = (int)in_sym[((b * IH + (oy * 2 + i)) * IW + (ox * 2 + j)) * CIN + c];
        int w = wsym[n * CO + co];              // scalar (uniform)
        int g = convT[w * NC + s];              // uniform 1KB row
        mybins[g] = (unsigned char)(mybins[g] + 1);
    }

    ScanU8 sc; sc.init(mybins);
    int t = sc.pop();
    for (int j = 1; j < N; ++j) {
        int x = sc.pop();
        int t2 = add_lut[x * NC + t];
        if (j < N - 2) {
            int y = sc.peek();
            if (t2 > y) { sc.consume_min(); sc.insert(t2); t = y; }
            else t = t2;
        } else t = t2;
    }
    out[pos * CO + co] = (OT)relu_lut[bias_lut[t * CO + co]];
}

__global__ __launch_bounds__(64) void k_conv1(
    const unsigned short* in, const int* wsym, const unsigned short* convT,
    const int* add_lut, const int* bias, const int* relu, unsigned short* out)
{
    conv_body<unsigned short, unsigned short, 1, 6, 32, 32, 14, 14>(
        in, wsym, convT, add_lut, bias, relu, out);
}

__global__ __launch_bounds__(64) void k_conv2(
    const unsigned short* in, const int* wsym, const unsigned short* convT,
    const int* add_lut, const int* bias, const int* relu, int* out)
{
    conv_body<unsigned short, int, 6, 16, 14, 14, 5, 5>(
        in, wsym, convT, add_lut, bias, relu, out);
}

// ===========================================================================
// Symbolic FC — R2 verbatim (distinct names for attribution only).
// ===========================================================================
template<int M, int K, bool PERM>
__device__ __forceinline__ void fc_body(
    const int* __restrict__ in_sym,
    const int* __restrict__ wsym,      // (M, K)
    const int* __restrict__ fc_lut,    // (NC, NC)
    const int* __restrict__ add_lut,   // (NC, NC)
    const int* __restrict__ bias_lut,  // (NC, M)
    const int* __restrict__ relu_lut,  // (NC,)
    int* __restrict__ out)             // (B, M)
{
    __shared__ __align__(16) unsigned char bins[64 * NC];   // 32 KB
    int tid = threadIdx.x;
    uint32_t* bz = (uint32_t*)bins;
    for (int i = 0; i < 128; ++i) bz[i * 64 + tid] = 0u;

    int id = blockIdx.x * 64 + tid;
    int m = id % M;
    int b = id / M;

    unsigned char* mybins = bins + tid * NC;
    for (int k = 0; k < K; ++k) {
        int xaddr;
        if (PERM) { int c = k / 25, yx = k % 25; xaddr = b * 400 + yx * 16 + c; }
        else      { xaddr = b * K + k; }
        int v = fc_lut[in_sym[xaddr] * NC + wsym[m * K + k]];
        mybins[v] = (unsigned char)(mybins[v] + 1);
    }

    ScanU8 sc; sc.init(mybins);
    int t = sc.pop();
    for (int s = 1; s < K; ++s) t = add_lut[sc.pop() * NC + t];
    out[id] = relu_lut[bias_lut[t * M + m]];
}

__global__ __launch_bounds__(64) void k_fc1(
    const int* in, const int* wsym, const int* fc_lut, const int* add_lut,
    const int* bias, const int* relu, int* out)
{
    fc_body<120, 400, true>(in, wsym, fc_lut, add_lut, bias, relu, out);
}

__global__ __launch_bounds__(64) void k_fc2(
    const int* in, const int* wsym, const int* fc_lut, const int* add_lut,
    const int* bias, const int* relu, int* out)
{
    fc_body<84, 120, false>(in, wsym, fc_lut, add_lut, bias, relu, out);
}

// ===========================================================================
// Head — R1-verified.
// ===========================================================================
__global__ __launch_bounds__(64) void k_head(
    const int* __restrict__ f2_syms,   // (128, 84)
    const float* __restrict__ cent,    // (NC,)
    const float* __restrict__ w,       // (10, 84)
    const float* __restrict__ bias,    // (10,)
    float* __restrict__ out)           // (128, 10)
{
    int b = blockIdx.x * 64 + threadIdx.x;
    float acc[10];
#pragma unroll
    for (int o = 0; o < 10; ++o) acc[o] = bias[o];
    for (int k = 0; k < 84; ++k) {
        float f = cent[f2_syms[b * 84 + k]];
#pragma unroll
        for (int o = 0; o < 10; ++o) acc[o] += f * w[o * 84 + k];
    }
    float mx = acc[0];
#pragma unroll
    for (int o = 1; o < 10; ++o) mx = fmaxf(mx, acc[o]);
    float s = 0.f;
#pragma unroll
    for (int o = 0; o < 10; ++o) { acc[o] = expf(acc[o] - mx); s += acc[o]; }
    float inv = 1.f / s;
#pragma unroll
    for (int o = 0; o < 10; ++o) out[b * 10 + o] = acc[o] * inv;
}

// ===========================================================================
extern "C" void kernel_launch(void* const* d_in, const int* in_sizes, int n_in,
                              void* d_out, int out_size, void* d_ws, size_t ws_size,
                              hipStream_t stream)
{
    const float* x_bat  = (const float*)d_in[0];
    const float* cent   = (const float*)d_in[1];
    const int* conv_lut = (const int*)d_in[2];
    const int* fc_lut   = (const int*)d_in[3];
    const int* add_lut  = (const int*)d_in[4];
    const int* relu_lut = (const int*)d_in[5];
    const int* c1_bias  = (const int*)d_in[6];
    const int* c2_bias  = (const int*)d_in[7];
    const int* f1_bias  = (const int*)d_in[8];
    const int* f2_bias  = (const int*)d_in[9];
    const int* c1f      = (const int*)d_in[10];
    const int* c2f      = (const int*)d_in[11];
    const int* f1f      = (const int*)d_in[12];
    const int* f2f      = (const int*)d_in[13];
    const float* fc3_w  = (const float*)d_in[14];
    const float* fc3_b  = (const float*)d_in[15];
    float* out = (float*)d_out;

    char* ws = (char*)d_ws;
    unsigned short* convT = (unsigned short*)(ws);            // 512 KB
    unsigned short* sym0  = (unsigned short*)(ws + 524288);   // 256 KB (u16)
    unsigned short* c1o   = (unsigned short*)(ws + 786432);   // 1176 KB (u16)
    int* c2o = (int*)(ws + 786432 + 1204224);                 // 200 KB
    int* f1o = (int*)(ws + 786432 + 1204224 + 204800);        //  60 KB
    int* f2o = (int*)(ws + 786432 + 1204224 + 204800 + 61440);//  42 KB
    // peak ws use ~2.23 MB (<= R3's proven 2.29 MB)

    k_transpose_pack<<<64, 256, 0, stream>>>(conv_lut, convT);
    k_discretize<<<512, 256, 0, stream>>>(x_bat, cent, sym0);
    // conv1: 6 co x 392 pos-groups
    k_conv1<<<2352, 64, 0, stream>>>(sym0, c1f, convT, add_lut, c1_bias, relu_lut, c1o);
    // conv2: 16 co x 50 pos-groups
    k_conv2<<<800, 64, 0, stream>>>(c1o, c2f, convT, add_lut, c2_bias, relu_lut, c2o);
    k_fc1<<<240, 64, 0, stream>>>(c2o, f1f, fc_lut, add_lut, f1_bias, relu_lut, f1o);
    k_fc2<<<168, 64, 0, stream>>>(f1o, f2f, fc_lut, add_lut, f2_bias, relu_lut, f2o);
    k_head<<<2, 64, 0, stream>>>(f2o, cent, fc3_w, fc3_b, out);
}